// Round 18
// baseline (379.155 us; speedup 1.0000x reference)
//
#include <hip/hip_runtime.h>
#include <hip/hip_bf16.h>

typedef short short8 __attribute__((ext_vector_type(8)));
typedef float f32x4 __attribute__((ext_vector_type(4)));
typedef _Float16 h2 __attribute__((ext_vector_type(2)));
typedef __fp16 fp16x2 __attribute__((ext_vector_type(2)));

#if __has_builtin(__builtin_elementwise_fma)
#define FMA2H(a, b, c) __builtin_elementwise_fma((a), (b), (c))
#else
#define FMA2H(a, b, c) ((a) * (b) + (c))
#endif

typedef const unsigned int __attribute__((address_space(1))) u32_g;
typedef unsigned int __attribute__((address_space(3))) u32_s;
#define GLDS16(gp, lp) __builtin_amdgcn_global_load_lds((u32_g*)(gp), (u32_s*)(lp), 16, 0, 0)

namespace {
constexpr int Bn = 2, Cn = 64, Dn = 16, Hn = 64, Wn = 64;
constexpr int Gn = 2, Kn = 27, GCn = 32;
constexpr int DHW = Dn * Hn * Wn;                 // 65536
constexpr int OCn = 216;                          // 162 off + 54 mask
constexpr int PD = 18, PH = 66, PW = 66;
constexpr float EPS = 1e-5f;

// conv d-slice: 4h x 66w rows of 128B (64ch bf16)
constexpr int SROWS = 4 * 66;                     // 264
constexpr int SLICE_B = SROWS * 128;              // 33,792

constexpr size_t XPADH_OFF = 0;
constexpr size_t XPADH_B   = (size_t)Bn * PD * PH * PW * Cn * 2;   // 20,072,448
constexpr size_t WFRAG_OFF = XPADH_OFF + XPADH_B;
constexpr size_t WFRAG_B   = (size_t)54 * 16 * 64 * 16;            // 884,736
constexpr size_t WV_OFF    = WFRAG_OFF + WFRAG_B;
constexpr size_t WV_B      = 64 * 64 * 4;
constexpr size_t CONV_OFF  = WV_OFF + WV_B;
constexpr size_t CONV_B    = (size_t)Bn * OCn * DHW * 2;           // 56,623,104
constexpr size_t V_OFF     = CONV_OFF + CONV_B;
constexpr size_t V_B       = (size_t)Bn * Gn * DHW * GCn * 2;      // f16
constexpr size_t SAMP_OFF  = V_OFF + V_B;
constexpr size_t SAMP_B    = (size_t)Bn * Gn * DHW * GCn * 2;      // bf16; reused as nvh
constexpr size_t STAT_OFF  = SAMP_OFF + SAMP_B;   // 256 floats: [b][sum64|sumsq64]
constexpr size_t VBH_OFF   = STAT_OFF + 4096;
constexpr size_t VFRAG_OFF = VBH_OFF + 256;       // 512 short8 = 8KB
constexpr size_t OFRAG_OFF = VFRAG_OFF + 8192;
constexpr size_t PFRAG_OFF = OFRAG_OFF + 8192;
// t (bf16, 16.7MB) reuses the xpadh region (dead after conv_mfma)
}

__device__ inline float b2f(short s) {
  union { float f; unsigned u; } x; x.u = ((unsigned)(unsigned short)s) << 16; return x.f;
}
__device__ inline short f2b(float f) {
  __hip_bfloat16 h = __float2bfloat16(f);
  union { __hip_bfloat16 h; short s; } x; x.h = h; return x.s;
}
__device__ inline int iclamp(int v, int lo, int hi) { return v < lo ? lo : (v > hi ? hi : v); }
__device__ inline h2 u2h2(unsigned u) {
  union { unsigned u; h2 h; } x; x.u = u; return x.h;
}
__device__ inline unsigned h2u(h2 h) {
  union { unsigned u; h2 h; } x; x.h = h; return x.u;
}
__device__ inline h2 pkrtz(float a, float b) {
#if __has_builtin(__builtin_amdgcn_cvt_pkrtz)
  union { fp16x2 p; h2 h; } x;
  x.p = __builtin_amdgcn_cvt_pkrtz(a, b);
  return x.h;
#else
  return (h2){(_Float16)a, (_Float16)b};
#endif
}

// ---- zero-fill padded input volume ----
__global__ __launch_bounds__(256) void zerofill(uint4* __restrict__ p, int n16) {
  int i = blockIdx.x * 256 + threadIdx.x;
  if (i < n16) p[i] = make_uint4(0, 0, 0, 0);
}

// ---- transpose-pad x [b,c,d,h,w] f32 -> xpadh [b,dz,hy,wx,c] bf16 (interior) ----
__global__ __launch_bounds__(256) void fillpad(const float* __restrict__ x,
                                               __hip_bfloat16* __restrict__ xpadh) {
  int tid = threadIdx.x;
  int w5 = tid & 31, cq = tid >> 5;
  int p = blockIdx.x * 32 + w5;
  int b = blockIdx.y;
  int w = p & 63, h = (p >> 6) & 63, d = p >> 12;
  const float* xb = x + ((size_t)b * 64 + cq * 8) * DHW + p;
  short8 o8;
#pragma unroll
  for (int j = 0; j < 8; ++j) o8[j] = f2b(xb[(size_t)j * DHW]);
  __hip_bfloat16* ob = xpadh + (size_t)b * (PD * PH * PW * 64)
      + ((((size_t)(d + 1) * 66) + (h + 1)) * 66 + (w + 1)) * 64 + cq * 8;
  *(short8*)ob = o8;
}

// ---- fold pre 1x1 into conv weights (MFMA fragment order) and value projection ----
__global__ __launch_bounds__(256) void fold_weights(
    const float* __restrict__ pre_w, const float* __restrict__ in_proj_w,
    const float* __restrict__ off_w, const float* __restrict__ mask_w,
    short8* __restrict__ Wfrag, float* __restrict__ Wv) {
  int i = blockIdx.x * 256 + threadIdx.x;
  if (i < 64 * 64) {
    int o = i >> 6, c = i & 63;
    float s = 0.f;
    for (int cp = 0; cp < 64; ++cp) s += in_proj_w[o * 64 + cp] * pre_w[cp * 64 + c];
    Wv[i] = s;
    return;
  }
  int t = i - 64 * 64;
  if (t >= 54 * 16 * 64) return;
  int l = t & 63; int rest = t >> 6;
  int mt = rest & 15; int ks = rest >> 4;
  int oc = mt * 16 + (l & 15);
  int tap = ks >> 1;
  int c0 = (ks & 1) * 32 + (l >> 4) * 8;
  float vals[8] = {0.f, 0.f, 0.f, 0.f, 0.f, 0.f, 0.f, 0.f};
  if (oc < OCn) {
    const float* cw = (oc < 162) ? (off_w + (size_t)oc * 64 * 27)
                                 : (mask_w + (size_t)(oc - 162) * 64 * 27);
#pragma unroll 1
    for (int cp = 0; cp < 64; ++cp) {
      float wv = cw[cp * 27 + tap];
      const float* pr = pre_w + cp * 64 + c0;
#pragma unroll
      for (int j = 0; j < 8; ++j) vals[j] += wv * pr[j];
    }
  }
  short8 o8;
#pragma unroll
  for (int j = 0; j < 8; ++j) o8[j] = f2b(vals[j]);
  Wfrag[t] = o8;
}

// ---- pack 64x64 matrices into MFMA A-fragment order (bf16) + f16 bias ----
// also zeroes the stat accumulator (256 floats)
__global__ __launch_bounds__(256) void packfrag(
    const float* __restrict__ Wv, const float* __restrict__ Wout,
    const float* __restrict__ Wpost, const float* __restrict__ vb,
    short8* __restrict__ vfrag, short8* __restrict__ ofrag,
    short8* __restrict__ pfrag, h2* __restrict__ vbh, float* __restrict__ stat) {
  int i = blockIdx.x * 256 + threadIdx.x;              // grid 6 -> 1536
  if (i < 32) vbh[i] = pkrtz(vb[2 * i], vb[2 * i + 1]);
  if (i >= 256 && i < 512) stat[i - 256] = 0.f;
  int which = i >> 9;
  int t = i & 511;
  int l = t & 63, mt = (t >> 6) & 3, ks = t >> 8;
  int m = mt * 16 + (l & 15);
  int k0 = ks * 32 + (l >> 4) * 8;
  const float* W = (which == 0) ? Wv : (which == 1) ? Wout : Wpost;
  short8 o;
#pragma unroll
  for (int j = 0; j < 8; ++j) o[j] = f2b(W[m * 64 + k0 + j]);
  if (which == 0) vfrag[t] = o;
  else if (which == 1) ofrag[t] = o;
  else pfrag[t] = o;
}

// ================= shared tail-GEMM pieces (M=64,K=64,N=256/block) =========
#define GEMM_MFMA_BODY(FRAG)                                                  \
  int wid = tid >> 6, l = tid & 63, lm = l & 15, lk = l >> 4;                 \
  f32x4 acc[4][4];                                                            \
  _Pragma("unroll")                                                           \
  for (int mt = 0; mt < 4; ++mt)                                              \
    _Pragma("unroll")                                                         \
    for (int nt = 0; nt < 4; ++nt) acc[mt][nt] = (f32x4){0.f, 0.f, 0.f, 0.f}; \
  _Pragma("unroll")                                                           \
  for (int ks = 0; ks < 2; ++ks) {                                            \
    short8 af[4], bf[4];                                                      \
    _Pragma("unroll")                                                         \
    for (int mt = 0; mt < 4; ++mt) af[mt] = FRAG[(ks * 4 + mt) * 64 + l];     \
    _Pragma("unroll")                                                         \
    for (int nt = 0; nt < 4; ++nt) {                                          \
      int sr = wid * 64 + nt * 16 + lm;                                       \
      int us = ks * 4 + lk;                                                   \
      bf[nt] = *(const short8*)(stg + sr * 128 + ((us ^ (sr & 7)) << 4));     \
    }                                                                         \
    _Pragma("unroll")                                                         \
    for (int mt = 0; mt < 4; ++mt)                                            \
      _Pragma("unroll")                                                       \
      for (int nt = 0; nt < 4; ++nt)                                          \
        acc[mt][nt] = __builtin_amdgcn_mfma_f32_16x16x32_bf16(af[mt], bf[nt], acc[mt][nt], 0, 0, 0); \
  }

// ---- vproj: v = Wv @ x + b from xpadh rows; writes v f16 [bg][p][32] ----
__global__ __launch_bounds__(256) void vproj_mfma(
    const char* __restrict__ xpadh, const short8* __restrict__ vfrag,
    const h2* __restrict__ vbh, _Float16* __restrict__ v) {
  __shared__ char stg[32768];
  __shared__ char bnc[256 * 144];
  int tid = threadIdx.x;
  int p0 = blockIdx.x * 256, b = blockIdx.y;
  const char* xb = xpadh + (size_t)b * (PD * PH * PW * 128);
#pragma unroll
  for (int it = 0; it < 8; ++it) {
    int idx = it * 256 + tid;
    int s = idx >> 3, slot = idx & 7;
    int p = p0 + s, w = p & 63, h = (p >> 6) & 63, d = p >> 12;
    const char* g = xb + ((((size_t)(d + 1)) * 66 + (h + 1)) * 66 + (w + 1)) * 128 + slot * 16;
    *(uint4*)(stg + s * 128 + ((slot ^ (s & 7)) << 4)) = *(const uint4*)g;
  }
  __syncthreads();
  GEMM_MFMA_BODY(vfrag)
#pragma unroll
  for (int mt = 0; mt < 4; ++mt)
#pragma unroll
    for (int nt = 0; nt < 4; ++nt)
#pragma unroll
      for (int r = 0; r < 4; ++r) {
        int pos = wid * 64 + nt * 16 + lm;
        int oc = mt * 16 + lk * 4 + r;
        *(_Float16*)(bnc + pos * 144 + oc * 2) = (_Float16)acc[mt][nt][r];
      }
  __syncthreads();
  {
    int p = p0 + tid;
    const unsigned* brow = (const unsigned*)(bnc + tid * 144);
    char* vb0 = (char*)v + ((size_t)(b * 2 + 0) * DHW + p) * 64;
    char* vb1 = (char*)v + ((size_t)(b * 2 + 1) * DHW + p) * 64;
#pragma unroll
    for (int s = 0; s < 8; ++s) {
      uint4 ov;
      unsigned* po = (unsigned*)&ov;
#pragma unroll
      for (int j = 0; j < 4; ++j) {
        h2 hv = u2h2(brow[s * 4 + j]) + vbh[s * 4 + j];
        po[j] = h2u(hv);
      }
      if (s < 4) *(uint4*)(vb0 + s * 16) = ov;
      else       *(uint4*)(vb1 + (s - 4) * 16) = ov;
    }
  }
}

// ---- MFMA implicit-GEMM 3x3x3 conv (unchanged from round 17) ----
__global__ __launch_bounds__(512, 4) void conv_mfma(
    const char* __restrict__ xpadh, const char* __restrict__ wfrag,
    const float* __restrict__ off_b, const float* __restrict__ mask_b,
    __hip_bfloat16* __restrict__ convout) {
  __shared__ char lds[2 * SLICE_B];                // 67,584 B -> 2 blocks/CU
  int tid = threadIdx.x;
  int h0 = blockIdx.x * 2, d = blockIdx.y, b = blockIdx.z;

  int wid = tid >> 6, l = tid & 63;
  int wm = wid & 3, wn = wid >> 2;
  int lm = l & 15, lk = l >> 4;
  const char* abase = wfrag + ((size_t)((wm * 4) * 64 + l)) * 16;
  const char* xb = xpadh + (size_t)b * (PD * PH * PW * 128);

  f32x4 acc[4][4];
#pragma unroll
  for (int mt = 0; mt < 4; ++mt)
#pragma unroll
    for (int nt = 0; nt < 4; ++nt) acc[mt][nt] = (f32x4){0.f, 0.f, 0.f, 0.f};

  short8 A0[4], B0[4];

#define LOADA(KS)                                                             \
  {                                                                           \
    const char* ap_ = abase + (KS) * 16384;                                   \
    _Pragma("unroll")                                                         \
    for (int mt = 0; mt < 4; ++mt) A0[mt] = *(const short8*)(ap_ + mt * 1024); \
  }
#define STAGE(DD, BUF)                                                        \
  {                                                                           \
    char* db_ = lds + (BUF) * SLICE_B + (wid << 10);                          \
    _Pragma("unroll")                                                         \
    for (int it = 0; it < 5; ++it) {                                          \
      int idx = it * 512 + tid;                                               \
      if (idx < SROWS * 8) {                                                  \
        int s_ = idx >> 3, slot_ = idx & 7;                                   \
        int hp_ = s_ / 66, wx_ = s_ - hp_ * 66;                               \
        int sslot_ = slot_ ^ (s_ & 7);                                        \
        const char* g_ = xb + ((((size_t)(d + (DD))) * 66 + (h0 + hp_)) * 66 + wx_) * 128 + sslot_ * 16; \
        GLDS16(g_, db_ + it * 8192);                                          \
      }                                                                       \
    }                                                                         \
  }

  STAGE(0, 0)
  LOADA(0)
  __syncthreads();

#pragma unroll 1
  for (int dd = 0; dd < 3; ++dd) {
    int buf = dd & 1;
    if (dd < 2) STAGE(dd + 1, buf ^ 1)
    const char* slice = lds + buf * SLICE_B;

#pragma unroll 1
    for (int tl = 0; tl < 9; ++tl) {
      int dh = tl / 3, dw = tl - dh * 3;
      int srow = (wn + dh) * 66 + dw;
#pragma unroll
      for (int ch = 0; ch < 2; ++ch) {
        int ks = dd * 18 + tl * 2 + ch;
        int uslot = 4 * ch + lk;
#pragma unroll
        for (int nt = 0; nt < 4; ++nt) {
          int sr = srow + nt * 16 + lm;
          B0[nt] = *(const short8*)(slice + sr * 128 + ((uslot ^ (sr & 7)) << 4));
        }
        __builtin_amdgcn_s_setprio(1);
#pragma unroll
        for (int mt = 0; mt < 4; ++mt)
#pragma unroll
          for (int nt = 0; nt < 4; ++nt)
            acc[mt][nt] = __builtin_amdgcn_mfma_f32_16x16x32_bf16(A0[mt], B0[nt], acc[mt][nt], 0, 0, 0);
        __builtin_amdgcn_s_setprio(0);
        if (ks + 1 < 54) LOADA(ks + 1)
      }
    }
    __syncthreads();
  }
#undef LOADA
#undef STAGE

  int pbase = d * 4096 + (h0 + wn) * 64;
#pragma unroll
  for (int mt = 0; mt < 4; ++mt) {
    int oc0 = wm * 64 + mt * 16 + lk * 4;
#pragma unroll
    for (int r = 0; r < 4; ++r) {
      int oc = oc0 + r;
      if (oc < OCn) {
        float bias = (oc < 162) ? off_b[oc] : mask_b[oc - 162];
        size_t orow = ((size_t)b * OCn + oc) * DHW + pbase;
#pragma unroll
        for (int nt = 0; nt < 4; ++nt)
          convout[orow + nt * 16 + lm] = __float2bfloat16(acc[mt][nt][r] + bias);
      }
    }
  }
}

// ---- deformable trilinear sampling + fused mask softmax (bf16 output) ----
// 4 lanes per (p,g) x 8 channels; geometry computed ONCE per quad (lane q
// handles taps k=4*kb+q) and broadcast via quad shfl; 28th dummy tap has
// ek=0 with in-bounds clamped coords. 64-pos blocks; XCD-swizzled grid.
__global__ __launch_bounds__(256) void dcn_sample(
    const __hip_bfloat16* __restrict__ convout, const _Float16* __restrict__ v,
    short* __restrict__ sampled) {
  __shared__ short offm[108 * 64];                 // 13,824 B
  int tid = threadIdx.x;
  int id = blockIdx.x;                             // 4096 blocks
  int bg = (id & 7) >> 1;
  int p0 = (((id >> 3) << 1) + (id & 1)) * 64;
  int b = bg >> 1, g = bg & 1;

  const __hip_bfloat16* cb = convout + (size_t)b * OCn * DHW;
#pragma unroll 1
  for (int idx = tid; idx < 108 * 8; idx += 256) {
    int row = idx >> 3, col = idx & 7;
    int oc = (row < 81) ? (g * 81 + row) : (162 + g * Kn + (row - 81));
    *(uint4*)(offm + row * 64 + col * 8) = *(const uint4*)(cb + (size_t)oc * DHW + p0 + col * 8);
  }
  __syncthreads();

  int pl = tid >> 2, q = tid & 3;
  int p = p0 + pl;
  int w = p & 63, h = (p >> 6) & 63, d = p >> 12;

  float msum = 0.f;
  h2 acc[4];
#pragma unroll
  for (int j = 0; j < 4; ++j) acc[j] = (h2){(_Float16)0.f, (_Float16)0.f};
  const char* vg = (const char*)v + ((size_t)bg * DHW * GCn + q * 8) * 2;

#pragma unroll 1
  for (int kb = 0; kb < 7; ++kb) {
    int k = kb * 4 + q;
    int kc = (k < Kn) ? k : (Kn - 1);
    float offd = b2f(offm[(3 * kc + 0) * 64 + pl]);
    float offh = b2f(offm[(3 * kc + 1) * 64 + pl]);
    float offw = b2f(offm[(3 * kc + 2) * 64 + pl]);
    float pd = (float)(d + (kc / 9) - 1) + offd * 0.5f;
    float ph = (float)(h + ((kc / 3) % 3) - 1) + offh;
    float pw = (float)(w + (kc % 3) - 1) + offw;
    float fd = floorf(pd), fh = floorf(ph), fw = floorf(pw);
    float td = pd - fd, th = ph - fh, tw = pw - fw;
    int d0 = (int)fd, h0 = (int)fh, w0 = (int)fw;
    float ek = (k < Kn) ? __expf(b2f(offm[(81 + kc) * 64 + pl])) : 0.f;
    msum += ek;

    float wd0 = ((unsigned)d0 < (unsigned)Dn) ? (1.f - td) * ek : 0.f;
    float wd1 = ((unsigned)(d0 + 1) < (unsigned)Dn) ? td * ek : 0.f;
    float wh0 = ((unsigned)h0 < (unsigned)Hn) ? (1.f - th) : 0.f;
    float wh1 = ((unsigned)(h0 + 1) < (unsigned)Hn) ? th : 0.f;
    float ww0 = ((unsigned)w0 < (unsigned)Wn) ? (1.f - tw) : 0.f;
    float ww1 = ((unsigned)(w0 + 1) < (unsigned)Wn) ? tw : 0.f;
    int dr0 = iclamp(d0, 0, Dn - 1) << 18, dr1 = iclamp(d0 + 1, 0, Dn - 1) << 18;
    int hr0 = iclamp(h0, 0, Hn - 1) << 12, hr1 = iclamp(h0 + 1, 0, Hn - 1) << 12;
    int wc0 = iclamp(w0, 0, Wn - 1) << 6,  wc1 = iclamp(w0 + 1, 0, Wn - 1) << 6;
    float wdh00 = wd0 * wh0, wdh01 = wd0 * wh1, wdh10 = wd1 * wh0, wdh11 = wd1 * wh1;

    int boff[8];
    unsigned wuu[8];
    boff[0] = dr0 + hr0 + wc0; wuu[0] = h2u(pkrtz(wdh00 * ww0, wdh00 * ww0));
    boff[1] = dr0 + hr0 + wc1; wuu[1] = h2u(pkrtz(wdh00 * ww1, wdh00 * ww1));
    boff[2] = dr0 + hr1 + wc0; wuu[2] = h2u(pkrtz(wdh01 * ww0, wdh01 * ww0));
    boff[3] = dr0 + hr1 + wc1; wuu[3] = h2u(pkrtz(wdh01 * ww1, wdh01 * ww1));
    boff[4] = dr1 + hr0 + wc0; wuu[4] = h2u(pkrtz(wdh10 * ww0, wdh10 * ww0));
    boff[5] = dr1 + hr0 + wc1; wuu[5] = h2u(pkrtz(wdh10 * ww1, wdh10 * ww1));
    boff[6] = dr1 + hr1 + wc0; wuu[6] = h2u(pkrtz(wdh11 * ww0, wdh11 * ww0));
    boff[7] = dr1 + hr1 + wc1; wuu[7] = h2u(pkrtz(wdh11 * ww1, wdh11 * ww1));

#pragma unroll
    for (int j = 0; j < 4; ++j) {                  // consume tap kb*4+j
#pragma unroll
      for (int c = 0; c < 8; ++c) {
        int bo = __shfl(boff[c], j, 4);
        unsigned wu = (unsigned)__shfl((int)wuu[c], j, 4);
        h2 w2 = u2h2(wu);
        uint4 u_ = *(const uint4*)(vg + bo);
        acc[0] = FMA2H(u2h2(u_.x), w2, acc[0]);
        acc[1] = FMA2H(u2h2(u_.y), w2, acc[1]);
        acc[2] = FMA2H(u2h2(u_.z), w2, acc[2]);
        acc[3] = FMA2H(u2h2(u_.w), w2, acc[3]);
      }
    }
  }

  msum += __shfl_xor(msum, 1);
  msum += __shfl_xor(msum, 2);
  float rs = 1.f / msum;
  short8 o8;
#pragma unroll
  for (int j = 0; j < 4; ++j) {
    o8[2 * j]     = f2b((float)acc[j][0] * rs);
    o8[2 * j + 1] = f2b((float)acc[j][1] * rs);
  }
  *(short8*)((char*)sampled + ((size_t)bg * DHW + p) * 64 + q * 16) = o8;
}

// ---- outproj: t(bf16, ch-major) = Wout @ sampled + ob via MFMA ----
// fused instance-norm partial sums -> stat (atomics)
__global__ __launch_bounds__(256) void outproj_mfma(
    const short* __restrict__ sampled, const short8* __restrict__ ofrag,
    const float* __restrict__ ob, __hip_bfloat16* __restrict__ t,
    float* __restrict__ stat) {
  __shared__ char stg[32768];
  __shared__ char bnc[256 * 144];
  __shared__ float red[128];
  int tid = threadIdx.x;
  int p0 = blockIdx.x * 256, b = blockIdx.y;
  if (tid < 128) red[tid] = 0.f;
#pragma unroll
  for (int it = 0; it < 8; ++it) {
    int idx = it * 256 + tid;
    int s = idx >> 3, slot = idx & 7;
    int g = slot >> 2;
    const char* src = (const char*)sampled + ((size_t)(b * 2 + g) * DHW + p0 + s) * 64 + (slot & 3) * 16;
    *(uint4*)(stg + s * 128 + ((slot ^ (s & 7)) << 4)) = *(const uint4*)src;
  }
  __syncthreads();
  GEMM_MFMA_BODY(ofrag)
#pragma unroll
  for (int mt = 0; mt < 4; ++mt)
#pragma unroll
    for (int r = 0; r < 4; ++r) {
      int oc = mt * 16 + lk * 4 + r;
      float bias = ob[oc];
#pragma unroll
      for (int nt = 0; nt < 4; ++nt) {
        int pos = wid * 64 + nt * 16 + lm;
        *(short*)(bnc + pos * 144 + oc * 2) = f2b(acc[mt][nt][r] + bias);
      }
    }
  __syncthreads();
  {
    int c = tid & 63, pq = tid >> 6;
    short* trow = (short*)t + ((size_t)b * 64 + c) * DHW + p0 + pq * 64;
    float s = 0.f, ss = 0.f;
#pragma unroll
    for (int s8 = 0; s8 < 8; ++s8) {
      short8 o8;
#pragma unroll
      for (int j = 0; j < 8; ++j) {
        short sv = *(const short*)(bnc + (pq * 64 + s8 * 8 + j) * 144 + c * 2);
        o8[j] = sv;
        float fv = b2f(sv);
        s += fv; ss += fv * fv;
      }
      *(short8*)(trow + s8 * 8) = o8;
    }
    atomicAdd(&red[c], s);
    atomicAdd(&red[64 + c], ss);
  }
  __syncthreads();
  if (tid < 128) atomicAdd(&stat[b * 128 + tid], red[tid]);
}

// ---- norm + gelu -> nvh (bf16, pos-major [b][p][64]); finalizes stats ----
__global__ __launch_bounds__(256) void normgelu(
    const __hip_bfloat16* __restrict__ t, const float* __restrict__ stat,
    const float* __restrict__ gamma, const float* __restrict__ beta,
    short* __restrict__ nvh) {
  int p = blockIdx.x * 256 + threadIdx.x;
  int b = blockIdx.y;
  short o[64];
#pragma unroll
  for (int c = 0; c < Cn; ++c) {
    float mu = stat[b * 128 + c] * (1.f / (float)DHW);
    float var = stat[b * 128 + 64 + c] * (1.f / (float)DHW) - mu * mu;
    float rstd = rsqrtf(var + EPS);
    float tv = b2f(((const short*)t)[((size_t)b * Cn + c) * DHW + p]);
    float yv = (tv - mu) * rstd * gamma[c] + beta[c];
    float u = 0.7978845608028654f * (yv + 0.044715f * yv * yv * yv);
    float e = __expf(2.f * u);
    float th = 1.f - 2.f / (e + 1.f);
    o[c] = f2b(0.5f * yv * (1.f + th));
  }
  short* dst = nvh + ((size_t)b * DHW + p) * 64;
#pragma unroll
  for (int s8 = 0; s8 < 8; ++s8) {
    short8 o8;
#pragma unroll
    for (int j = 0; j < 8; ++j) o8[j] = o[s8 * 8 + j];
    *(short8*)(dst + s8 * 8) = o8;
  }
}

// ---- post 1x1 via MFMA + gated residual -> out (f32 ch-major) ----
__global__ __launch_bounds__(256) void post_mfma(
    const short* __restrict__ nvh, const short8* __restrict__ pfrag,
    const float* __restrict__ x, const float* __restrict__ gate,
    float* __restrict__ out) {
  __shared__ char stg[32768];
  __shared__ char bnc[256 * 144];
  int tid = threadIdx.x;
  int p0 = blockIdx.x * 256, b = blockIdx.y;
#pragma unroll
  for (int it = 0; it < 8; ++it) {
    int idx = it * 256 + tid;
    int s = idx >> 3, slot = idx & 7;
    const char* src = (const char*)nvh + ((size_t)b * DHW + p0 + s) * 128 + slot * 16;
    *(uint4*)(stg + s * 128 + ((slot ^ (s & 7)) << 4)) = *(const uint4*)src;
  }
  __syncthreads();
  GEMM_MFMA_BODY(pfrag)
#pragma unroll
  for (int mt = 0; mt < 4; ++mt)
#pragma unroll
    for (int nt = 0; nt < 4; ++nt)
#pragma unroll
      for (int r = 0; r < 4; ++r) {
        int pos = wid * 64 + nt * 16 + lm;
        int oc = mt * 16 + lk * 4 + r;
        *(short*)(bnc + pos * 144 + oc * 2) = f2b(acc[mt][nt][r]);
      }
  __syncthreads();
  {
    float sg = 1.f / (1.f + __expf(-gate[0]));
    int c = tid & 63, pq = tid >> 6;
    size_t base = ((size_t)b * 64 + c) * DHW + p0 + pq * 64;
    const float4* x4 = (const float4*)(x + base);
    float4* o4 = (float4*)(out + base);
#pragma unroll
    for (int qd = 0; qd < 16; ++qd) {
      float4 xv = x4[qd];
      float v0 = b2f(*(const short*)(bnc + (pq * 64 + qd * 4 + 0) * 144 + c * 2));
      float v1 = b2f(*(const short*)(bnc + (pq * 64 + qd * 4 + 1) * 144 + c * 2));
      float v2 = b2f(*(const short*)(bnc + (pq * 64 + qd * 4 + 2) * 144 + c * 2));
      float v3 = b2f(*(const short*)(bnc + (pq * 64 + qd * 4 + 3) * 144 + c * 2));
      o4[qd] = make_float4(xv.x + sg * v0, xv.y + sg * v1, xv.z + sg * v2, xv.w + sg * v3);
    }
  }
}

extern "C" void kernel_launch(void* const* d_in, const int* in_sizes, int n_in,
                              void* d_out, int out_size, void* d_ws, size_t ws_size,
                              hipStream_t stream) {
  const float* x          = (const float*)d_in[0];
  const float* gate       = (const float*)d_in[1];
  const float* pre_w      = (const float*)d_in[2];
  const float* post_w     = (const float*)d_in[3];
  const float* in_proj_w  = (const float*)d_in[4];
  const float* in_proj_b  = (const float*)d_in[5];
  const float* out_proj_w = (const float*)d_in[6];
  const float* out_proj_b = (const float*)d_in[7];
  const float* off_w      = (const float*)d_in[8];
  const float* off_b      = (const float*)d_in[9];
  const float* mask_w     = (const float*)d_in[10];
  const float* mask_b     = (const float*)d_in[11];
  const float* in_gamma   = (const float*)d_in[12];
  const float* in_beta    = (const float*)d_in[13];

  char* ws = (char*)d_ws;
  __hip_bfloat16* xpadh = (__hip_bfloat16*)(ws + XPADH_OFF);
  short8* Wfrag  = (short8*)(ws + WFRAG_OFF);
  float* Wv      = (float*)(ws + WV_OFF);
  __hip_bfloat16* convout = (__hip_bfloat16*)(ws + CONV_OFF);
  _Float16* v    = (_Float16*)(ws + V_OFF);
  short* sampled = (short*)(ws + SAMP_OFF);
  short* nvh     = (short*)(ws + SAMP_OFF);        // reuses sampled (dead after outproj)
  float* stat    = (float*)(ws + STAT_OFF);
  h2* vbh        = (h2*)(ws + VBH_OFF);
  short8* vfrag  = (short8*)(ws + VFRAG_OFF);
  short8* ofrag  = (short8*)(ws + OFRAG_OFF);
  short8* pfrag  = (short8*)(ws + PFRAG_OFF);
  __hip_bfloat16* t = (__hip_bfloat16*)(ws + XPADH_OFF);   // reuses xpadh region
  float* out = (float*)d_out;

  int zf16 = (int)(XPADH_B / 16);
  zerofill<<<(zf16 + 255) / 256, 256, 0, stream>>>((uint4*)xpadh, zf16);
  fillpad<<<dim3(DHW / 32, Bn), 256, 0, stream>>>(x, xpadh);
  int foldN = (64 * 64 + 54 * 16 * 64 + 255) / 256;
  fold_weights<<<foldN, 256, 0, stream>>>(pre_w, in_proj_w, off_w, mask_w, Wfrag, Wv);
  packfrag<<<6, 256, 0, stream>>>(Wv, out_proj_w, post_w, in_proj_b,
                                  vfrag, ofrag, pfrag, vbh, stat);
  vproj_mfma<<<dim3(DHW / 256, Bn), 256, 0, stream>>>((const char*)xpadh, vfrag, vbh, v);
  conv_mfma<<<dim3(32, 16, 2), 512, 0, stream>>>((const char*)xpadh, (const char*)Wfrag,
                                                 off_b, mask_b, convout);
  dcn_sample<<<4096, 256, 0, stream>>>(convout, v, sampled);
  outproj_mfma<<<dim3(DHW / 256, Bn), 256, 0, stream>>>(sampled, ofrag, out_proj_b, t, stat);
  normgelu<<<dim3(DHW / 256, Bn), 256, 0, stream>>>(t, stat, in_gamma, in_beta, nvh);
  post_mfma<<<dim3(DHW / 256, Bn), 256, 0, stream>>>(nvh, pfrag, x, gate, out);
}

// Round 19
// 325.973 us; speedup vs baseline: 1.1631x; 1.1631x over previous
//
#include <hip/hip_runtime.h>
#include <hip/hip_bf16.h>

typedef short short8 __attribute__((ext_vector_type(8)));
typedef float f32x4 __attribute__((ext_vector_type(4)));
typedef _Float16 h2 __attribute__((ext_vector_type(2)));
typedef __fp16 fp16x2 __attribute__((ext_vector_type(2)));

#if __has_builtin(__builtin_elementwise_fma)
#define FMA2H(a, b, c) __builtin_elementwise_fma((a), (b), (c))
#else
#define FMA2H(a, b, c) ((a) * (b) + (c))
#endif

typedef const unsigned int __attribute__((address_space(1))) u32_g;
typedef unsigned int __attribute__((address_space(3))) u32_s;
#define GLDS16(gp, lp) __builtin_amdgcn_global_load_lds((u32_g*)(gp), (u32_s*)(lp), 16, 0, 0)

namespace {
constexpr int Bn = 2, Cn = 64, Dn = 16, Hn = 64, Wn = 64;
constexpr int Gn = 2, Kn = 27, GCn = 32;
constexpr int DHW = Dn * Hn * Wn;                 // 65536
constexpr int OCn = 216;                          // 162 off + 54 mask
constexpr int PD = 18, PH = 66, PW = 66;
constexpr float EPS = 1e-5f;

// conv d-slice: 4h x 66w rows of 128B (64ch bf16)
constexpr int SROWS = 4 * 66;                     // 264
constexpr int SLICE_B = SROWS * 128;              // 33,792

constexpr size_t XPADH_OFF = 0;
constexpr size_t XPADH_B   = (size_t)Bn * PD * PH * PW * Cn * 2;   // 20,072,448
constexpr size_t WFRAG_OFF = XPADH_OFF + XPADH_B;
constexpr size_t WFRAG_B   = (size_t)54 * 16 * 64 * 16;            // 884,736
constexpr size_t WV_OFF    = WFRAG_OFF + WFRAG_B;
constexpr size_t WV_B      = 64 * 64 * 4;
constexpr size_t CONV_OFF  = WV_OFF + WV_B;
constexpr size_t CONV_B    = (size_t)Bn * OCn * DHW * 2;           // 56,623,104
constexpr size_t V_OFF     = CONV_OFF + CONV_B;
constexpr size_t V_B       = (size_t)Bn * Gn * DHW * GCn * 2;      // f16
constexpr size_t SAMP_OFF  = V_OFF + V_B;
constexpr size_t SAMP_B    = (size_t)Bn * Gn * DHW * GCn * 2;      // bf16; reused as nvh
constexpr size_t STAT_OFF  = SAMP_OFF + SAMP_B;   // 256 floats: [b][sum64|sumsq64]
constexpr size_t VBH_OFF   = STAT_OFF + 4096;
constexpr size_t VFRAG_OFF = VBH_OFF + 256;       // 512 short8 = 8KB
constexpr size_t OFRAG_OFF = VFRAG_OFF + 8192;
constexpr size_t PFRAG_OFF = OFRAG_OFF + 8192;
// t (bf16, 16.7MB) reuses the xpadh region (dead after conv_mfma)
}

__device__ inline float b2f(short s) {
  union { float f; unsigned u; } x; x.u = ((unsigned)(unsigned short)s) << 16; return x.f;
}
__device__ inline short f2b(float f) {
  __hip_bfloat16 h = __float2bfloat16(f);
  union { __hip_bfloat16 h; short s; } x; x.h = h; return x.s;
}
__device__ inline int iclamp(int v, int lo, int hi) { return v < lo ? lo : (v > hi ? hi : v); }
__device__ inline h2 u2h2(unsigned u) {
  union { unsigned u; h2 h; } x; x.u = u; return x.h;
}
__device__ inline unsigned h2u(h2 h) {
  union { unsigned u; h2 h; } x; x.h = h; return x.u;
}
__device__ inline h2 pkrtz(float a, float b) {
#if __has_builtin(__builtin_amdgcn_cvt_pkrtz)
  union { fp16x2 p; h2 h; } x;
  x.p = __builtin_amdgcn_cvt_pkrtz(a, b);
  return x.h;
#else
  return (h2){(_Float16)a, (_Float16)b};
#endif
}

// ---- zero-fill padded input volume ----
__global__ __launch_bounds__(256) void zerofill(uint4* __restrict__ p, int n16) {
  int i = blockIdx.x * 256 + threadIdx.x;
  if (i < n16) p[i] = make_uint4(0, 0, 0, 0);
}

// ---- transpose-pad x [b,c,d,h,w] f32 -> xpadh [b,dz,hy,wx,c] bf16 (interior) ----
__global__ __launch_bounds__(256) void fillpad(const float* __restrict__ x,
                                               __hip_bfloat16* __restrict__ xpadh) {
  int tid = threadIdx.x;
  int w5 = tid & 31, cq = tid >> 5;
  int p = blockIdx.x * 32 + w5;
  int b = blockIdx.y;
  int w = p & 63, h = (p >> 6) & 63, d = p >> 12;
  const float* xb = x + ((size_t)b * 64 + cq * 8) * DHW + p;
  short8 o8;
#pragma unroll
  for (int j = 0; j < 8; ++j) o8[j] = f2b(xb[(size_t)j * DHW]);
  __hip_bfloat16* ob = xpadh + (size_t)b * (PD * PH * PW * 64)
      + ((((size_t)(d + 1) * 66) + (h + 1)) * 66 + (w + 1)) * 64 + cq * 8;
  *(short8*)ob = o8;
}

// ---- fold pre 1x1 into conv weights (MFMA fragment order) and value projection ----
__global__ __launch_bounds__(256) void fold_weights(
    const float* __restrict__ pre_w, const float* __restrict__ in_proj_w,
    const float* __restrict__ off_w, const float* __restrict__ mask_w,
    short8* __restrict__ Wfrag, float* __restrict__ Wv) {
  int i = blockIdx.x * 256 + threadIdx.x;
  if (i < 64 * 64) {
    int o = i >> 6, c = i & 63;
    float s = 0.f;
    for (int cp = 0; cp < 64; ++cp) s += in_proj_w[o * 64 + cp] * pre_w[cp * 64 + c];
    Wv[i] = s;
    return;
  }
  int t = i - 64 * 64;
  if (t >= 54 * 16 * 64) return;
  int l = t & 63; int rest = t >> 6;
  int mt = rest & 15; int ks = rest >> 4;
  int oc = mt * 16 + (l & 15);
  int tap = ks >> 1;
  int c0 = (ks & 1) * 32 + (l >> 4) * 8;
  float vals[8] = {0.f, 0.f, 0.f, 0.f, 0.f, 0.f, 0.f, 0.f};
  if (oc < OCn) {
    const float* cw = (oc < 162) ? (off_w + (size_t)oc * 64 * 27)
                                 : (mask_w + (size_t)(oc - 162) * 64 * 27);
#pragma unroll 1
    for (int cp = 0; cp < 64; ++cp) {
      float wv = cw[cp * 27 + tap];
      const float* pr = pre_w + cp * 64 + c0;
#pragma unroll
      for (int j = 0; j < 8; ++j) vals[j] += wv * pr[j];
    }
  }
  short8 o8;
#pragma unroll
  for (int j = 0; j < 8; ++j) o8[j] = f2b(vals[j]);
  Wfrag[t] = o8;
}

// ---- pack 64x64 matrices into MFMA A-fragment order (bf16) + f16 bias ----
// also zeroes the stat accumulator (256 floats)
__global__ __launch_bounds__(256) void packfrag(
    const float* __restrict__ Wv, const float* __restrict__ Wout,
    const float* __restrict__ Wpost, const float* __restrict__ vb,
    short8* __restrict__ vfrag, short8* __restrict__ ofrag,
    short8* __restrict__ pfrag, h2* __restrict__ vbh, float* __restrict__ stat) {
  int i = blockIdx.x * 256 + threadIdx.x;              // grid 6 -> 1536
  if (i < 32) vbh[i] = pkrtz(vb[2 * i], vb[2 * i + 1]);
  if (i >= 256 && i < 512) stat[i - 256] = 0.f;
  int which = i >> 9;
  int t = i & 511;
  int l = t & 63, mt = (t >> 6) & 3, ks = t >> 8;
  int m = mt * 16 + (l & 15);
  int k0 = ks * 32 + (l >> 4) * 8;
  const float* W = (which == 0) ? Wv : (which == 1) ? Wout : Wpost;
  short8 o;
#pragma unroll
  for (int j = 0; j < 8; ++j) o[j] = f2b(W[m * 64 + k0 + j]);
  if (which == 0) vfrag[t] = o;
  else if (which == 1) ofrag[t] = o;
  else pfrag[t] = o;
}

// ================= shared tail-GEMM pieces (M=64,K=64,N=256/block) =========
#define GEMM_MFMA_BODY(FRAG)                                                  \
  int wid = tid >> 6, l = tid & 63, lm = l & 15, lk = l >> 4;                 \
  f32x4 acc[4][4];                                                            \
  _Pragma("unroll")                                                           \
  for (int mt = 0; mt < 4; ++mt)                                              \
    _Pragma("unroll")                                                         \
    for (int nt = 0; nt < 4; ++nt) acc[mt][nt] = (f32x4){0.f, 0.f, 0.f, 0.f}; \
  _Pragma("unroll")                                                           \
  for (int ks = 0; ks < 2; ++ks) {                                            \
    short8 af[4], bf[4];                                                      \
    _Pragma("unroll")                                                         \
    for (int mt = 0; mt < 4; ++mt) af[mt] = FRAG[(ks * 4 + mt) * 64 + l];     \
    _Pragma("unroll")                                                         \
    for (int nt = 0; nt < 4; ++nt) {                                          \
      int sr = wid * 64 + nt * 16 + lm;                                       \
      int us = ks * 4 + lk;                                                   \
      bf[nt] = *(const short8*)(stg + sr * 128 + ((us ^ (sr & 7)) << 4));     \
    }                                                                         \
    _Pragma("unroll")                                                         \
    for (int mt = 0; mt < 4; ++mt)                                            \
      _Pragma("unroll")                                                       \
      for (int nt = 0; nt < 4; ++nt)                                          \
        acc[mt][nt] = __builtin_amdgcn_mfma_f32_16x16x32_bf16(af[mt], bf[nt], acc[mt][nt], 0, 0, 0); \
  }

// ---- vproj: v = Wv @ x + b from xpadh rows; writes v f16 [bg][p][32] ----
__global__ __launch_bounds__(256) void vproj_mfma(
    const char* __restrict__ xpadh, const short8* __restrict__ vfrag,
    const h2* __restrict__ vbh, _Float16* __restrict__ v) {
  __shared__ char stg[32768];
  __shared__ char bnc[256 * 144];
  int tid = threadIdx.x;
  int p0 = blockIdx.x * 256, b = blockIdx.y;
  const char* xb = xpadh + (size_t)b * (PD * PH * PW * 128);
#pragma unroll
  for (int it = 0; it < 8; ++it) {
    int idx = it * 256 + tid;
    int s = idx >> 3, slot = idx & 7;
    int p = p0 + s, w = p & 63, h = (p >> 6) & 63, d = p >> 12;
    const char* g = xb + ((((size_t)(d + 1)) * 66 + (h + 1)) * 66 + (w + 1)) * 128 + slot * 16;
    *(uint4*)(stg + s * 128 + ((slot ^ (s & 7)) << 4)) = *(const uint4*)g;
  }
  __syncthreads();
  GEMM_MFMA_BODY(vfrag)
#pragma unroll
  for (int mt = 0; mt < 4; ++mt)
#pragma unroll
    for (int nt = 0; nt < 4; ++nt)
#pragma unroll
      for (int r = 0; r < 4; ++r) {
        int pos = wid * 64 + nt * 16 + lm;
        int oc = mt * 16 + lk * 4 + r;
        *(_Float16*)(bnc + pos * 144 + oc * 2) = (_Float16)acc[mt][nt][r];
      }
  __syncthreads();
  {
    int p = p0 + tid;
    const unsigned* brow = (const unsigned*)(bnc + tid * 144);
    char* vb0 = (char*)v + ((size_t)(b * 2 + 0) * DHW + p) * 64;
    char* vb1 = (char*)v + ((size_t)(b * 2 + 1) * DHW + p) * 64;
#pragma unroll
    for (int s = 0; s < 8; ++s) {
      uint4 ov;
      unsigned* po = (unsigned*)&ov;
#pragma unroll
      for (int j = 0; j < 4; ++j) {
        h2 hv = u2h2(brow[s * 4 + j]) + vbh[s * 4 + j];
        po[j] = h2u(hv);
      }
      if (s < 4) *(uint4*)(vb0 + s * 16) = ov;
      else       *(uint4*)(vb1 + (s - 4) * 16) = ov;
    }
  }
}

// ---- MFMA implicit-GEMM 3x3x3 conv (round-17 version) ----
__global__ __launch_bounds__(512, 4) void conv_mfma(
    const char* __restrict__ xpadh, const char* __restrict__ wfrag,
    const float* __restrict__ off_b, const float* __restrict__ mask_b,
    __hip_bfloat16* __restrict__ convout) {
  __shared__ char lds[2 * SLICE_B];                // 67,584 B -> 2 blocks/CU
  int tid = threadIdx.x;
  int h0 = blockIdx.x * 2, d = blockIdx.y, b = blockIdx.z;

  int wid = tid >> 6, l = tid & 63;
  int wm = wid & 3, wn = wid >> 2;
  int lm = l & 15, lk = l >> 4;
  const char* abase = wfrag + ((size_t)((wm * 4) * 64 + l)) * 16;
  const char* xb = xpadh + (size_t)b * (PD * PH * PW * 128);

  f32x4 acc[4][4];
#pragma unroll
  for (int mt = 0; mt < 4; ++mt)
#pragma unroll
    for (int nt = 0; nt < 4; ++nt) acc[mt][nt] = (f32x4){0.f, 0.f, 0.f, 0.f};

  short8 A0[4], B0[4];

#define LOADA(KS)                                                             \
  {                                                                           \
    const char* ap_ = abase + (KS) * 16384;                                   \
    _Pragma("unroll")                                                         \
    for (int mt = 0; mt < 4; ++mt) A0[mt] = *(const short8*)(ap_ + mt * 1024); \
  }
#define STAGE(DD, BUF)                                                        \
  {                                                                           \
    char* db_ = lds + (BUF) * SLICE_B + (wid << 10);                          \
    _Pragma("unroll")                                                         \
    for (int it = 0; it < 5; ++it) {                                          \
      int idx = it * 512 + tid;                                               \
      if (idx < SROWS * 8) {                                                  \
        int s_ = idx >> 3, slot_ = idx & 7;                                   \
        int hp_ = s_ / 66, wx_ = s_ - hp_ * 66;                               \
        int sslot_ = slot_ ^ (s_ & 7);                                        \
        const char* g_ = xb + ((((size_t)(d + (DD))) * 66 + (h0 + hp_)) * 66 + wx_) * 128 + sslot_ * 16; \
        GLDS16(g_, db_ + it * 8192);                                          \
      }                                                                       \
    }                                                                         \
  }

  STAGE(0, 0)
  LOADA(0)
  __syncthreads();

#pragma unroll 1
  for (int dd = 0; dd < 3; ++dd) {
    int buf = dd & 1;
    if (dd < 2) STAGE(dd + 1, buf ^ 1)
    const char* slice = lds + buf * SLICE_B;

#pragma unroll 1
    for (int tl = 0; tl < 9; ++tl) {
      int dh = tl / 3, dw = tl - dh * 3;
      int srow = (wn + dh) * 66 + dw;
#pragma unroll
      for (int ch = 0; ch < 2; ++ch) {
        int ks = dd * 18 + tl * 2 + ch;
        int uslot = 4 * ch + lk;
#pragma unroll
        for (int nt = 0; nt < 4; ++nt) {
          int sr = srow + nt * 16 + lm;
          B0[nt] = *(const short8*)(slice + sr * 128 + ((uslot ^ (sr & 7)) << 4));
        }
        __builtin_amdgcn_s_setprio(1);
#pragma unroll
        for (int mt = 0; mt < 4; ++mt)
#pragma unroll
          for (int nt = 0; nt < 4; ++nt)
            acc[mt][nt] = __builtin_amdgcn_mfma_f32_16x16x32_bf16(A0[mt], B0[nt], acc[mt][nt], 0, 0, 0);
        __builtin_amdgcn_s_setprio(0);
        if (ks + 1 < 54) LOADA(ks + 1)
      }
    }
    __syncthreads();
  }
#undef LOADA
#undef STAGE

  int pbase = d * 4096 + (h0 + wn) * 64;
#pragma unroll
  for (int mt = 0; mt < 4; ++mt) {
    int oc0 = wm * 64 + mt * 16 + lk * 4;
#pragma unroll
    for (int r = 0; r < 4; ++r) {
      int oc = oc0 + r;
      if (oc < OCn) {
        float bias = (oc < 162) ? off_b[oc] : mask_b[oc - 162];
        size_t orow = ((size_t)b * OCn + oc) * DHW + pbase;
#pragma unroll
        for (int nt = 0; nt < 4; ++nt)
          convout[orow + nt * 16 + lm] = __float2bfloat16(acc[mt][nt][r] + bias);
      }
    }
  }
}

// ---- deformable trilinear sampling + fused mask softmax (round-17 version) ----
// 4 lanes per (p,g) x 8 channels; 64-pos blocks; XCD-swizzled 1D grid.
__global__ __launch_bounds__(256) void dcn_sample(
    const __hip_bfloat16* __restrict__ convout, const _Float16* __restrict__ v,
    short* __restrict__ sampled) {
  __shared__ short offm[108 * 64];                 // 13,824 B
  int tid = threadIdx.x;
  int id = blockIdx.x;                             // 4096 blocks
  int bg = (id & 7) >> 1;                          // 2 XCDs per (b,g): L2 locality
  int p0 = (((id >> 3) << 1) + (id & 1)) * 64;
  int b = bg >> 1, g = bg & 1;

  const __hip_bfloat16* cb = convout + (size_t)b * OCn * DHW;
#pragma unroll 1
  for (int idx = tid; idx < 108 * 8; idx += 256) {
    int row = idx >> 3, col = idx & 7;
    int oc = (row < 81) ? (g * 81 + row) : (162 + g * Kn + (row - 81));
    *(uint4*)(offm + row * 64 + col * 8) = *(const uint4*)(cb + (size_t)oc * DHW + p0 + col * 8);
  }
  __syncthreads();

  int pl = tid >> 2, q = tid & 3;
  int p = p0 + pl;
  int w = p & 63, h = (p >> 6) & 63, d = p >> 12;

  float msum = 0.f;
  h2 acc[4];
#pragma unroll
  for (int j = 0; j < 4; ++j) acc[j] = (h2){(_Float16)0.f, (_Float16)0.f};
  const char* vg = (const char*)v + ((size_t)bg * DHW * GCn + q * 8) * 2;

#pragma unroll 1
  for (int k = 0; k < Kn; ++k) {
    float offd = b2f(offm[(3 * k + 0) * 64 + pl]);
    float offh = b2f(offm[(3 * k + 1) * 64 + pl]);
    float offw = b2f(offm[(3 * k + 2) * 64 + pl]);
    float pd = (float)(d + (k / 9) - 1) + offd * 0.5f;
    float ph = (float)(h + ((k / 3) % 3) - 1) + offh;
    float pw = (float)(w + (k % 3) - 1) + offw;
    float fd = floorf(pd), fh = floorf(ph), fw = floorf(pw);
    float td = pd - fd, th = ph - fh, tw = pw - fw;
    int d0 = (int)fd, h0 = (int)fh, w0 = (int)fw;
    float ek = __expf(b2f(offm[(81 + k) * 64 + pl]));
    msum += ek;

    float wd0 = ((unsigned)d0 < (unsigned)Dn) ? (1.f - td) * ek : 0.f;
    float wd1 = ((unsigned)(d0 + 1) < (unsigned)Dn) ? td * ek : 0.f;
    float wh0 = ((unsigned)h0 < (unsigned)Hn) ? (1.f - th) : 0.f;
    float wh1 = ((unsigned)(h0 + 1) < (unsigned)Hn) ? th : 0.f;
    float ww0 = ((unsigned)w0 < (unsigned)Wn) ? (1.f - tw) : 0.f;
    float ww1 = ((unsigned)(w0 + 1) < (unsigned)Wn) ? tw : 0.f;
    int dr0 = iclamp(d0, 0, Dn - 1) << 18, dr1 = iclamp(d0 + 1, 0, Dn - 1) << 18;
    int hr0 = iclamp(h0, 0, Hn - 1) << 12, hr1 = iclamp(h0 + 1, 0, Hn - 1) << 12;
    int wc0 = iclamp(w0, 0, Wn - 1) << 6,  wc1 = iclamp(w0 + 1, 0, Wn - 1) << 6;
    float wdh00 = wd0 * wh0, wdh01 = wd0 * wh1, wdh10 = wd1 * wh0, wdh11 = wd1 * wh1;

#define CORNER(BOFF, WT)                                                \
    {                                                                   \
      _Float16 wh_ = (_Float16)(WT);                                    \
      h2 w2_ = {wh_, wh_};                                              \
      uint4 u_ = *(const uint4*)(vg + (BOFF));                          \
      acc[0] = FMA2H(u2h2(u_.x), w2_, acc[0]);                          \
      acc[1] = FMA2H(u2h2(u_.y), w2_, acc[1]);                          \
      acc[2] = FMA2H(u2h2(u_.z), w2_, acc[2]);                          \
      acc[3] = FMA2H(u2h2(u_.w), w2_, acc[3]);                          \
    }
    CORNER(dr0 + hr0 + wc0, wdh00 * ww0)
    CORNER(dr0 + hr0 + wc1, wdh00 * ww1)
    CORNER(dr0 + hr1 + wc0, wdh01 * ww0)
    CORNER(dr0 + hr1 + wc1, wdh01 * ww1)
    CORNER(dr1 + hr0 + wc0, wdh10 * ww0)
    CORNER(dr1 + hr0 + wc1, wdh10 * ww1)
    CORNER(dr1 + hr1 + wc0, wdh11 * ww0)
    CORNER(dr1 + hr1 + wc1, wdh11 * ww1)
#undef CORNER
  }

  float rs = 1.f / msum;
  short8 o8;
#pragma unroll
  for (int j = 0; j < 4; ++j) {
    o8[2 * j]     = f2b((float)acc[j][0] * rs);
    o8[2 * j + 1] = f2b((float)acc[j][1] * rs);
  }
  *(short8*)((char*)sampled + ((size_t)bg * DHW + p) * 64 + q * 16) = o8;
}

// ---- outproj: t(bf16, ch-major) = Wout @ sampled + ob via MFMA ----
// fused instance-norm partial sums -> stat (atomics)
__global__ __launch_bounds__(256) void outproj_mfma(
    const short* __restrict__ sampled, const short8* __restrict__ ofrag,
    const float* __restrict__ ob, __hip_bfloat16* __restrict__ t,
    float* __restrict__ stat) {
  __shared__ char stg[32768];
  __shared__ char bnc[256 * 144];
  __shared__ float red[128];
  int tid = threadIdx.x;
  int p0 = blockIdx.x * 256, b = blockIdx.y;
  if (tid < 128) red[tid] = 0.f;
#pragma unroll
  for (int it = 0; it < 8; ++it) {
    int idx = it * 256 + tid;
    int s = idx >> 3, slot = idx & 7;
    int g = slot >> 2;
    const char* src = (const char*)sampled + ((size_t)(b * 2 + g) * DHW + p0 + s) * 64 + (slot & 3) * 16;
    *(uint4*)(stg + s * 128 + ((slot ^ (s & 7)) << 4)) = *(const uint4*)src;
  }
  __syncthreads();
  GEMM_MFMA_BODY(ofrag)
#pragma unroll
  for (int mt = 0; mt < 4; ++mt)
#pragma unroll
    for (int r = 0; r < 4; ++r) {
      int oc = mt * 16 + lk * 4 + r;
      float bias = ob[oc];
#pragma unroll
      for (int nt = 0; nt < 4; ++nt) {
        int pos = wid * 64 + nt * 16 + lm;
        *(short*)(bnc + pos * 144 + oc * 2) = f2b(acc[mt][nt][r] + bias);
      }
    }
  __syncthreads();
  {
    int c = tid & 63, pq = tid >> 6;
    short* trow = (short*)t + ((size_t)b * 64 + c) * DHW + p0 + pq * 64;
    float s = 0.f, ss = 0.f;
#pragma unroll
    for (int s8 = 0; s8 < 8; ++s8) {
      short8 o8;
#pragma unroll
      for (int j = 0; j < 8; ++j) {
        short sv = *(const short*)(bnc + (pq * 64 + s8 * 8 + j) * 144 + c * 2);
        o8[j] = sv;
        float fv = b2f(sv);
        s += fv; ss += fv * fv;
      }
      *(short8*)(trow + s8 * 8) = o8;
    }
    atomicAdd(&red[c], s);
    atomicAdd(&red[64 + c], ss);
  }
  __syncthreads();
  if (tid < 128) atomicAdd(&stat[b * 128 + tid], red[tid]);
}

// ---- norm + gelu -> nvh (bf16, pos-major [b][p][64]); finalizes stats ----
__global__ __launch_bounds__(256) void normgelu(
    const __hip_bfloat16* __restrict__ t, const float* __restrict__ stat,
    const float* __restrict__ gamma, const float* __restrict__ beta,
    short* __restrict__ nvh) {
  int p = blockIdx.x * 256 + threadIdx.x;
  int b = blockIdx.y;
  short o[64];
#pragma unroll
  for (int c = 0; c < Cn; ++c) {
    float mu = stat[b * 128 + c] * (1.f / (float)DHW);
    float var = stat[b * 128 + 64 + c] * (1.f / (float)DHW) - mu * mu;
    float rstd = rsqrtf(var + EPS);
    float tv = b2f(((const short*)t)[((size_t)b * Cn + c) * DHW + p]);
    float yv = (tv - mu) * rstd * gamma[c] + beta[c];
    float u = 0.7978845608028654f * (yv + 0.044715f * yv * yv * yv);
    float e = __expf(2.f * u);
    float th = 1.f - 2.f / (e + 1.f);
    o[c] = f2b(0.5f * yv * (1.f + th));
  }
  short* dst = nvh + ((size_t)b * DHW + p) * 64;
#pragma unroll
  for (int s8 = 0; s8 < 8; ++s8) {
    short8 o8;
#pragma unroll
    for (int j = 0; j < 8; ++j) o8[j] = o[s8 * 8 + j];
    *(short8*)(dst + s8 * 8) = o8;
  }
}

// ---- post 1x1 via MFMA + gated residual -> out (f32 ch-major) ----
__global__ __launch_bounds__(256) void post_mfma(
    const short* __restrict__ nvh, const short8* __restrict__ pfrag,
    const float* __restrict__ x, const float* __restrict__ gate,
    float* __restrict__ out) {
  __shared__ char stg[32768];
  __shared__ char bnc[256 * 144];
  int tid = threadIdx.x;
  int p0 = blockIdx.x * 256, b = blockIdx.y;
#pragma unroll
  for (int it = 0; it < 8; ++it) {
    int idx = it * 256 + tid;
    int s = idx >> 3, slot = idx & 7;
    const char* src = (const char*)nvh + ((size_t)b * DHW + p0 + s) * 128 + slot * 16;
    *(uint4*)(stg + s * 128 + ((slot ^ (s & 7)) << 4)) = *(const uint4*)src;
  }
  __syncthreads();
  GEMM_MFMA_BODY(pfrag)
#pragma unroll
  for (int mt = 0; mt < 4; ++mt)
#pragma unroll
    for (int nt = 0; nt < 4; ++nt)
#pragma unroll
      for (int r = 0; r < 4; ++r) {
        int pos = wid * 64 + nt * 16 + lm;
        int oc = mt * 16 + lk * 4 + r;
        *(short*)(bnc + pos * 144 + oc * 2) = f2b(acc[mt][nt][r]);
      }
  __syncthreads();
  {
    float sg = 1.f / (1.f + __expf(-gate[0]));
    int c = tid & 63, pq = tid >> 6;
    size_t base = ((size_t)b * 64 + c) * DHW + p0 + pq * 64;
    const float4* x4 = (const float4*)(x + base);
    float4* o4 = (float4*)(out + base);
#pragma unroll
    for (int qd = 0; qd < 16; ++qd) {
      float4 xv = x4[qd];
      float v0 = b2f(*(const short*)(bnc + (pq * 64 + qd * 4 + 0) * 144 + c * 2));
      float v1 = b2f(*(const short*)(bnc + (pq * 64 + qd * 4 + 1) * 144 + c * 2));
      float v2 = b2f(*(const short*)(bnc + (pq * 64 + qd * 4 + 2) * 144 + c * 2));
      float v3 = b2f(*(const short*)(bnc + (pq * 64 + qd * 4 + 3) * 144 + c * 2));
      o4[qd] = make_float4(xv.x + sg * v0, xv.y + sg * v1, xv.z + sg * v2, xv.w + sg * v3);
    }
  }
}

extern "C" void kernel_launch(void* const* d_in, const int* in_sizes, int n_in,
                              void* d_out, int out_size, void* d_ws, size_t ws_size,
                              hipStream_t stream) {
  const float* x          = (const float*)d_in[0];
  const float* gate       = (const float*)d_in[1];
  const float* pre_w      = (const float*)d_in[2];
  const float* post_w     = (const float*)d_in[3];
  const float* in_proj_w  = (const float*)d_in[4];
  const float* in_proj_b  = (const float*)d_in[5];
  const float* out_proj_w = (const float*)d_in[6];
  const float* out_proj_b = (const float*)d_in[7];
  const float* off_w      = (const float*)d_in[8];
  const float* off_b      = (const float*)d_in[9];
  const float* mask_w     = (const float*)d_in[10];
  const float* mask_b     = (const float*)d_in[11];
  const float* in_gamma   = (const float*)d_in[12];
  const float* in_beta    = (const float*)d_in[13];

  char* ws = (char*)d_ws;
  __hip_bfloat16* xpadh = (__hip_bfloat16*)(ws + XPADH_OFF);
  short8* Wfrag  = (short8*)(ws + WFRAG_OFF);
  float* Wv      = (float*)(ws + WV_OFF);
  __hip_bfloat16* convout = (__hip_bfloat16*)(ws + CONV_OFF);
  _Float16* v    = (_Float16*)(ws + V_OFF);
  short* sampled = (short*)(ws + SAMP_OFF);
  short* nvh     = (short*)(ws + SAMP_OFF);        // reuses sampled (dead after outproj)
  float* stat    = (float*)(ws + STAT_OFF);
  h2* vbh        = (h2*)(ws + VBH_OFF);
  short8* vfrag  = (short8*)(ws + VFRAG_OFF);
  short8* ofrag  = (short8*)(ws + OFRAG_OFF);
  short8* pfrag  = (short8*)(ws + PFRAG_OFF);
  __hip_bfloat16* t = (__hip_bfloat16*)(ws + XPADH_OFF);   // reuses xpadh region
  float* out = (float*)d_out;

  int zf16 = (int)(XPADH_B / 16);
  zerofill<<<(zf16 + 255) / 256, 256, 0, stream>>>((uint4*)xpadh, zf16);
  fillpad<<<dim3(DHW / 32, Bn), 256, 0, stream>>>(x, xpadh);
  int foldN = (64 * 64 + 54 * 16 * 64 + 255) / 256;
  fold_weights<<<foldN, 256, 0, stream>>>(pre_w, in_proj_w, off_w, mask_w, Wfrag, Wv);
  packfrag<<<6, 256, 0, stream>>>(Wv, out_proj_w, post_w, in_proj_b,
                                  vfrag, ofrag, pfrag, vbh, stat);
  vproj_mfma<<<dim3(DHW / 256, Bn), 256, 0, stream>>>((const char*)xpadh, vfrag, vbh, v);
  conv_mfma<<<dim3(32, 16, 2), 512, 0, stream>>>((const char*)xpadh, (const char*)Wfrag,
                                                 off_b, mask_b, convout);
  dcn_sample<<<4096, 256, 0, stream>>>(convout, v, sampled);
  outproj_mfma<<<dim3(DHW / 256, Bn), 256, 0, stream>>>(sampled, ofrag, out_proj_b, t, stat);
  normgelu<<<dim3(DHW / 256, Bn), 256, 0, stream>>>(t, stat, in_gamma, in_beta, nvh);
  post_mfma<<<dim3(DHW / 256, Bn), 256, 0, stream>>>(nvh, pfrag, x, gate, out);
}